// Round 11
// baseline (442.903 us; speedup 1.0000x reference)
//
#include <hip/hip_runtime.h>
#include <hip/hip_cooperative_groups.h>

namespace cg = cooperative_groups;

// Problem constants (from reference setup_inputs)
#define B_   16
#define C_   64
#define HW_  65536   // 256*256
#define GRP  8       // batches per group (fp16 payload = 64 MiB in registers)
#define NBLK 1024    // 4 blocks/CU x 256 CUs (co-resident, 16 waves/CU)
#define NTHR 256

typedef float    f2_t __attribute__((ext_vector_type(2)));
typedef _Float16 h2_t __attribute__((ext_vector_type(2)));

// fast branch-free tanh: 1 - 2/(e^2z + 1), clamped
__device__ __forceinline__ float fast_tanh(float z) {
    z = fminf(fmaxf(z, -15.f), 15.f);
    float e = __expf(2.f * z);
    return 1.f - 2.f * __builtin_amdgcn_rcpf(e + 1.f);
}

// ---------------------------------------------------------------------------
// Persistent cooperative kernel. Each thread owns 2 consecutive pixels of one
// batch; x is read ONCE (kept as fp16 in 64 VGPRs), channel means reduced via
// in-register butterfly + LDS + one atomicAdd/channel/block, grid.sync, then
// output computed straight from registers. Two groups of 8 batches.
// ---------------------------------------------------------------------------
__global__ __launch_bounds__(NTHR, 4) void k_persist(
    const float* __restrict__ x,
    const float* __restrict__ theta_w, const float* __restrict__ theta_b,
    const float* __restrict__ g1_w,    const float* __restrict__ g1_b,
    const float* __restrict__ g2_w,    const float* __restrict__ g2_b,
    const float* __restrict__ phi_w,   const float* __restrict__ phi_b,
    float* __restrict__ gsums, float* __restrict__ out) {

    cg::grid_group grid = cg::this_grid();
    int t    = threadIdx.x;
    int bi   = blockIdx.x >> 7;                      // batch-in-group 0..7
    int pix  = ((blockIdx.x & 127) * NTHR + t) * 2;  // pixel pair
    int lane = t & 63, wid = t >> 6;

    __shared__ float wsum[4][C_];
    __shared__ float xn[C_], z1[C_], wsh[C_], pw[C_], pb[C_];
    __shared__ float hp[4][C_];
    __shared__ float bias_s;

    if (t < C_) { pw[t] = phi_w[t]; pb[t] = phi_b[t]; }
    float g2w0 = g2_w[0], g2b0 = g2_b[0];

    h2_t xs[C_];    // fp16 payload: 64 VGPRs, static indexing only

    for (int g = 0; g < 2; ++g) {
        int b = g * GRP + bi;
        const float* xb = x + (size_t)b * C_ * HW_ + pix;

        // ================= Phase A: load, stash fp16, reduce sums =========
#pragma unroll
        for (int k = 0; k < 8; ++k) {
            float pt[8];
#pragma unroll
            for (int i = 0; i < 8; ++i) {
                int c = k * 8 + i;
                f2_t v = *(const f2_t*)(xb + (size_t)c * HW_);
                h2_t h; h.x = (_Float16)v.x; h.y = (_Float16)v.y;
                xs[c] = h;
                pt[i] = v.x + v.y;
            }
            // 64-lane recursive-halving butterfly (static indices only).
            // End state: every lane holds sum over the wave of channel
            // k*8 + ((lane>>3)&7).
            {   // stage xor 32: bit5 selects kept half
                bool hi = (lane & 32) != 0;
                float a0 = hi ? pt[4] : pt[0], s0 = hi ? pt[0] : pt[4];
                float a1 = hi ? pt[5] : pt[1], s1 = hi ? pt[1] : pt[5];
                float a2 = hi ? pt[6] : pt[2], s2 = hi ? pt[2] : pt[6];
                float a3 = hi ? pt[7] : pt[3], s3 = hi ? pt[3] : pt[7];
                pt[0] = a0 + __shfl_xor(s0, 32, 64);
                pt[1] = a1 + __shfl_xor(s1, 32, 64);
                pt[2] = a2 + __shfl_xor(s2, 32, 64);
                pt[3] = a3 + __shfl_xor(s3, 32, 64);
            }
            {   // stage xor 16: bit4
                bool hi = (lane & 16) != 0;
                float a0 = hi ? pt[2] : pt[0], s0 = hi ? pt[0] : pt[2];
                float a1 = hi ? pt[3] : pt[1], s1 = hi ? pt[1] : pt[3];
                pt[0] = a0 + __shfl_xor(s0, 16, 64);
                pt[1] = a1 + __shfl_xor(s1, 16, 64);
            }
            float q;
            {   // stage xor 8: bit3
                bool hi = (lane & 8) != 0;
                float a = hi ? pt[1] : pt[0], s = hi ? pt[0] : pt[1];
                q = a + __shfl_xor(s, 8, 64);
            }
            q += __shfl_xor(q, 4, 64);
            q += __shfl_xor(q, 2, 64);
            q += __shfl_xor(q, 1, 64);
            if ((lane & 7) == 0)
                wsum[wid][k * 8 + ((lane >> 3) & 7)] = q;
        }
        __syncthreads();
        if (t < C_) {
            float gs = (wsum[0][t] + wsum[1][t]) + (wsum[2][t] + wsum[3][t]);
            atomicAdd(&gsums[b * C_ + t], gs);
        }

        grid.sync();

        // ================= Phase B: GCN math + output from registers ======
        int n = t & 63, q4 = t >> 6;
        if (t < C_) xn[t] = gsums[b * C_ + t] * (1.0f / (float)HW_);
        __syncthreads();
        float hpart = 0.f;
#pragma unroll
        for (int i = 0; i < 16; ++i) {
            int c = q4 * 16 + i;
            hpart += xn[c] * g1_w[n * C_ + c];
        }
        hp[q4][n] = hpart;
        __syncthreads();
        if (t < C_) {
            float h = g1_b[t] + (hp[0][t] + hp[1][t]) + (hp[2][t] + hp[3][t]);
            z1[t] = h * g2w0 + g2b0;
        }
        __syncthreads();
        float wpart = 0.f;
#pragma unroll
        for (int i = 0; i < 16; ++i) {
            int nn = q4 * 16 + i;
            wpart += z1[nn] * theta_w[nn * C_ + n];
        }
        hp[q4][n] = wpart;                       // reuse hp
        if (t == 0) {
            float bb = 0.f;
#pragma unroll
            for (int nn = 0; nn < C_; ++nn) bb += z1[nn] * theta_b[nn];
            bias_s = bb;
        }
        __syncthreads();
        if (t < C_) wsh[t] = (hp[0][t] + hp[1][t]) + (hp[2][t] + hp[3][t]);
        __syncthreads();

        float y0 = bias_s, y1 = bias_s;
#pragma unroll
        for (int c = 0; c < C_; ++c) {
            float w = wsh[c];
            y0 += w * (float)xs[c].x;
            y1 += w * (float)xs[c].y;
        }
        float* ob = out + (size_t)b * C_ * HW_ + pix;
#pragma unroll
        for (int c = 0; c < C_; ++c) {
            float a = pw[c], d = pb[c];
            f2_t r;
            r.x = fast_tanh(y0 * a + d + (float)xs[c].x);
            r.y = fast_tanh(y1 * a + d + (float)xs[c].y);
            __builtin_nontemporal_store(r, (f2_t*)(ob + (size_t)c * HW_));
        }
        // next group's Phase A follows with no grid sync (independent data);
        // __syncthreads inside Phase A guards the LDS reuse.
        __syncthreads();
    }
}

// ===========================================================================
// Fallback path (round-9 proven, 126 us): used only if coop launch fails.
// ===========================================================================
__global__ __launch_bounds__(256) void k_reduce_mean(
    const float* __restrict__ x, float* __restrict__ x_node) {
    int bc  = blockIdx.x;
    int tid = threadIdx.x;
    const float4* p4 = (const float4*)(x + (size_t)bc * HW_);
    float s = 0.f;
#pragma unroll
    for (int i = 0; i < 64; ++i) {
        float4 v = p4[tid + 256 * i];
        s += (v.x + v.y) + (v.z + v.w);
    }
#pragma unroll
    for (int off = 32; off; off >>= 1) s += __shfl_down(s, off, 64);
    __shared__ float ls[4];
    int wid = tid >> 6, lane = tid & 63;
    if (lane == 0) ls[wid] = s;
    __syncthreads();
    if (tid == 0)
        x_node[bc] = ((ls[0] + ls[1]) + (ls[2] + ls[3])) * (1.0f / (float)HW_);
}

__global__ __launch_bounds__(256) void k_fused_reg(
    const float* __restrict__ x, const float* __restrict__ x_node,
    const float* __restrict__ theta_w, const float* __restrict__ theta_b,
    const float* __restrict__ g1_w,    const float* __restrict__ g1_b,
    const float* __restrict__ g2_w,    const float* __restrict__ g2_b,
    const float* __restrict__ phi_w,   const float* __restrict__ phi_b,
    float* __restrict__ out) {
    __shared__ float xn[C_], z1[C_], wsh[C_], pw[C_], pb[C_];
    __shared__ float hp[4][C_];
    __shared__ float bias_s;

    int t = threadIdx.x;
    int b = blockIdx.x >> 7;
    int chunk = 127 - (blockIdx.x & 127);
    int pix = (chunk * 256 + t) * 2;

    int n = t & 63, q = t >> 6;
    if (t < C_) { xn[t] = x_node[b * C_ + t]; pw[t] = phi_w[t]; pb[t] = phi_b[t]; }
    __syncthreads();
    float hpart = 0.f;
#pragma unroll
    for (int i = 0; i < 16; ++i) {
        int c = q * 16 + i;
        hpart += xn[c] * g1_w[n * C_ + c];
    }
    hp[q][n] = hpart;
    __syncthreads();
    if (t < C_) {
        float h = g1_b[t] + (hp[0][t] + hp[1][t]) + (hp[2][t] + hp[3][t]);
        z1[t] = h * g2_w[0] + g2_b[0];
    }
    __syncthreads();
    float wpart = 0.f;
#pragma unroll
    for (int i = 0; i < 16; ++i) {
        int nn = q * 16 + i;
        wpart += z1[nn] * theta_w[nn * C_ + n];
    }
    hp[q][n] = wpart;
    if (t == 0) {
        float bb = 0.f;
#pragma unroll
        for (int nn = 0; nn < C_; ++nn) bb += z1[nn] * theta_b[nn];
        bias_s = bb;
    }
    __syncthreads();
    if (t < C_) wsh[t] = (hp[0][t] + hp[1][t]) + (hp[2][t] + hp[3][t]);
    __syncthreads();

    const float* xb = x + (size_t)b * C_ * HW_ + pix;
    f2_t xs[C_];
    float y0 = bias_s, y1 = bias_s;
#pragma unroll
    for (int c = 0; c < C_; ++c) {
        f2_t v = *(const f2_t*)(xb + (size_t)c * HW_);
        xs[c] = v;
        float w = wsh[c];
        y0 += w * v.x;
        y1 += w * v.y;
    }
    float* ob = out + (size_t)b * C_ * HW_ + pix;
#pragma unroll
    for (int c = 0; c < C_; ++c) {
        float a = pw[c], d = pb[c];
        f2_t r;
        r.x = fast_tanh(y0 * a + d + xs[c].x);
        r.y = fast_tanh(y1 * a + d + xs[c].y);
        __builtin_nontemporal_store(r, (f2_t*)(ob + (size_t)c * HW_));
    }
}

// ---------------------------------------------------------------------------
extern "C" void kernel_launch(void* const* d_in, const int* in_sizes, int n_in,
                              void* d_out, int out_size, void* d_ws, size_t ws_size,
                              hipStream_t stream) {
    const float* x       = (const float*)d_in[0];
    const float* theta_w = (const float*)d_in[1];
    const float* theta_b = (const float*)d_in[2];
    const float* g1_w    = (const float*)d_in[3];
    const float* g1_b    = (const float*)d_in[4];
    const float* g2_w    = (const float*)d_in[5];
    const float* g2_b    = (const float*)d_in[6];
    const float* phi_w   = (const float*)d_in[7];
    const float* phi_b   = (const float*)d_in[8];
    float* out = (float*)d_out;

    float* gsums  = (float*)d_ws;                 // B*C floats (atomic sums)
    float* x_node = gsums + B_ * C_;              // B*C floats (fallback)

    hipMemsetAsync(gsums, 0, B_ * C_ * sizeof(float), stream);

    void* args[] = {
        (void*)&x, (void*)&theta_w, (void*)&theta_b,
        (void*)&g1_w, (void*)&g1_b, (void*)&g2_w, (void*)&g2_b,
        (void*)&phi_w, (void*)&phi_b, (void*)&gsums, (void*)&out
    };
    hipError_t err = hipLaunchCooperativeKernel((void*)k_persist, dim3(NBLK),
                                                dim3(NTHR), args, 0, stream);
    if (err != hipSuccess) {
        // deterministic fallback: round-9 proven path
        k_reduce_mean<<<B_ * C_, 256, 0, stream>>>(x, x_node);
        k_fused_reg<<<B_ * (HW_ / 512), 256, 0, stream>>>(
            x, x_node, theta_w, theta_b, g1_w, g1_b, g2_w, g2_b,
            phi_w, phi_b, out);
    }
}

// Round 12
// 125.441 us; speedup vs baseline: 3.5308x; 3.5308x over previous
//
#include <hip/hip_runtime.h>
#include <hip/hip_bf16.h>

// Problem constants (from reference setup_inputs)
#define B_   16
#define C_   64
#define HW_  65536   // 256*256

typedef float    f2_t __attribute__((ext_vector_type(2)));
typedef _Float16 h2_t __attribute__((ext_vector_type(2)));

// fast branch-free tanh: 1 - 2/(e^2z + 1), clamped
__device__ __forceinline__ float fast_tanh(float z) {
    z = fminf(fmaxf(z, -15.f), 15.f);
    float e = __expf(2.f * z);
    return 1.f - 2.f * __builtin_amdgcn_rcpf(e + 1.f);
}

// ---------------------------------------------------------------------------
// Kernel 1: x_node[b,c] = mean over H*W of x[b,c,:,:]
// grid = B*C = 1024 blocks, 256 threads; float4 loads. No fences, no atomics.
// ---------------------------------------------------------------------------
__global__ __launch_bounds__(256) void k_reduce_mean(
    const float* __restrict__ x, float* __restrict__ x_node) {
    int bc  = blockIdx.x;                    // 0..1023  (b*64 + c)
    int tid = threadIdx.x;                   // 0..255
    const float4* p4 = (const float4*)(x + (size_t)bc * HW_);

    float s = 0.f;
#pragma unroll
    for (int i = 0; i < 64; ++i) {
        float4 v = p4[tid + 256 * i];
        s += (v.x + v.y) + (v.z + v.w);
    }
#pragma unroll
    for (int off = 32; off; off >>= 1) s += __shfl_down(s, off, 64);

    __shared__ float ls[4];
    int wid = tid >> 6, lane = tid & 63;
    if (lane == 0) ls[wid] = s;
    __syncthreads();
    if (tid == 0) {
        float t = (ls[0] + ls[1]) + (ls[2] + ls[3]);
        x_node[bc] = t * (1.0f / (float)HW_);
    }
}

// ---------------------------------------------------------------------------
// Kernel 2: fused GCN-math + y + phi + tanh, register version.
// Per-block redundant tiny GCN math, then 2 pixels/thread with the channel
// payload stashed as fp16 (h2_t xs[64] = 64 VGPRs instead of 128) so the
// kernel fits 4 waves/SIMD. y is accumulated from the fp32 loads (full
// precision); only the residual-add term is fp16-rounded (err ~2.4e-3,
// proven benign in round 10). Reversed chunk order for L3-freshest lines.
// grid = B * (HW/512) = 2048 blocks; 128 blocks per batch.
// ---------------------------------------------------------------------------
__global__ __launch_bounds__(256) void k_fused_reg(
    const float* __restrict__ x, const float* __restrict__ x_node,
    const float* __restrict__ theta_w, const float* __restrict__ theta_b,
    const float* __restrict__ g1_w,    const float* __restrict__ g1_b,
    const float* __restrict__ g2_w,    const float* __restrict__ g2_b,
    const float* __restrict__ phi_w,   const float* __restrict__ phi_b,
    float* __restrict__ out) {
    __shared__ float xn[C_], z1[C_], wsh[C_], pw[C_], pb[C_];
    __shared__ float hp[4][C_];
    __shared__ float bias_s;

    int t = threadIdx.x;
    int b = blockIdx.x >> 7;                 // 128 blocks per batch
    int chunk = 127 - (blockIdx.x & 127);    // reversed pixel order
    int pix = (chunk * 256 + t) * 2;

    // ---- per-block tiny GCN math (redundant, deterministic) ----
    int n = t & 63, q = t >> 6;
    if (t < C_) { xn[t] = x_node[b * C_ + t]; pw[t] = phi_w[t]; pb[t] = phi_b[t]; }
    __syncthreads();
    float hpart = 0.f;
#pragma unroll
    for (int i = 0; i < 16; ++i) {
        int c = q * 16 + i;
        hpart += xn[c] * g1_w[n * C_ + c];
    }
    hp[q][n] = hpart;
    __syncthreads();
    if (t < C_) {
        float h = g1_b[t] + (hp[0][t] + hp[1][t]) + (hp[2][t] + hp[3][t]);
        z1[t] = h * g2_w[0] + g2_b[0];
    }
    __syncthreads();
    float wpart = 0.f;
#pragma unroll
    for (int i = 0; i < 16; ++i) {
        int nn = q * 16 + i;
        wpart += z1[nn] * theta_w[nn * C_ + n];
    }
    hp[q][n] = wpart;                        // reuse hp
    if (t == 0) {
        float bb = 0.f;
#pragma unroll
        for (int nn = 0; nn < C_; ++nn) bb += z1[nn] * theta_b[nn];
        bias_s = bb;
    }
    __syncthreads();
    if (t < C_) wsh[t] = (hp[0][t] + hp[1][t]) + (hp[2][t] + hp[3][t]);
    __syncthreads();

    // ---- register pixel pass: fp32 loads, fp16 stash (64 VGPRs) ----
    const float* xb = x + (size_t)b * C_ * HW_ + pix;

    h2_t xs[C_];                             // 64 VGPRs payload
    float y0 = bias_s, y1 = bias_s;
#pragma unroll
    for (int c = 0; c < C_; ++c) {
        f2_t v = *(const f2_t*)(xb + (size_t)c * HW_);
        h2_t h; h.x = (_Float16)v.x; h.y = (_Float16)v.y;
        xs[c] = h;
        float w = wsh[c];
        y0 += w * v.x;                       // full-precision accumulation
        y1 += w * v.y;
    }

    float* ob = out + (size_t)b * C_ * HW_ + pix;
#pragma unroll
    for (int c = 0; c < C_; ++c) {
        float a = pw[c], d = pb[c];
        f2_t r;
        r.x = fast_tanh(y0 * a + d + (float)xs[c].x);
        r.y = fast_tanh(y1 * a + d + (float)xs[c].y);
        __builtin_nontemporal_store(r, (f2_t*)(ob + (size_t)c * HW_));
    }
}

// ---------------------------------------------------------------------------
extern "C" void kernel_launch(void* const* d_in, const int* in_sizes, int n_in,
                              void* d_out, int out_size, void* d_ws, size_t ws_size,
                              hipStream_t stream) {
    const float* x       = (const float*)d_in[0];
    const float* theta_w = (const float*)d_in[1];
    const float* theta_b = (const float*)d_in[2];
    const float* g1_w    = (const float*)d_in[3];
    const float* g1_b    = (const float*)d_in[4];
    const float* g2_w    = (const float*)d_in[5];
    const float* g2_b    = (const float*)d_in[6];
    const float* phi_w   = (const float*)d_in[7];
    const float* phi_b   = (const float*)d_in[8];
    float* out = (float*)d_out;

    float* x_node = (float*)d_ws;            // B*C floats

    k_reduce_mean<<<B_ * C_, 256, 0, stream>>>(x, x_node);
    k_fused_reg<<<B_ * (HW_ / 512), 256, 0, stream>>>(
        x, x_node, theta_w, theta_b, g1_w, g1_b, g2_w, g2_b,
        phi_w, phi_b, out);
}